// Round 10
// baseline (171.760 us; speedup 1.0000x reference)
//
#include <hip/hip_runtime.h>
#include <cstdint>

#define T_LEN 4096
#define S_DIM 308
#define S_PAD 320
#define E_DIM 126
#define NBATCH 32
#define NCHUNK 128
#define CHL 32
#define WARM 4     // contraction ~0.03-0.07/step -> <=1e-3 rel per chunk boundary
#define FH 136     // inH row stride (f16)
#define QSTR 336   // QL row stride (f16); conflicts handled by XOR block swizzle

typedef _Float16 half8 __attribute__((ext_vector_type(8)));
typedef float floatx4 __attribute__((ext_vector_type(4)));

union HU8 { uint4 u; half8 h; };
union HU1 { uint16_t u; _Float16 h; };

__device__ __forceinline__ half8 h8_from_u4(uint4 v) { HU8 t; t.u = v; return t.h; }

// ---- merged init: blocks 0..49 pack A-frags, 50..69 pack B-frags, 70 zeroes out ----
__global__ __launch_bounds__(256) void init_pack(const float* __restrict__ A,
                                                 const float* __restrict__ Bm,
                                                 uint32_t* __restrict__ Apk,
                                                 uint32_t* __restrict__ Bfr,
                                                 float* __restrict__ out) {
  int blk = blockIdx.x, tid = threadIdx.x;
  if (blk < 50) {
    int idx = blk * 256 + tid;                 // 200 tiles * 64 lanes
    int lane = idx & 63, tile = idx >> 6;
    int kt = tile % 10, nt = tile / 10;
    int n  = nt * 16 + (lane & 15);
    int k0 = kt * 32 + (lane >> 4) * 8;
    uint32_t wv[4];
#pragma unroll
    for (int jj = 0; jj < 4; jj++) {
      int ka = k0 + 2 * jj, kb = ka + 1;
      float x0 = (n < S_DIM && ka < S_DIM) ? A[ka * S_DIM + n] : 0.f;
      float x1 = (n < S_DIM && kb < S_DIM) ? A[kb * S_DIM + n] : 0.f;
      HU1 h0, h1; h0.h = (_Float16)x0; h1.h = (_Float16)x1;
      wv[jj] = (uint32_t)h0.u | ((uint32_t)h1.u << 16);
    }
    uint4 o; o.x = wv[0]; o.y = wv[1]; o.z = wv[2]; o.w = wv[3];
    ((uint4*)Apk)[idx] = o;
  } else if (blk < 70) {
    int idx = (blk - 50) * 256 + tid;          // 80 tiles * 64 lanes
    int lane = idx & 63, tile = idx >> 6;
    int kt = tile % 4, nt = tile / 4;
    int n  = nt * 16 + (lane & 15);
    int k0 = kt * 32 + (lane >> 4) * 8;
    uint32_t wv[4];
#pragma unroll
    for (int jj = 0; jj < 4; jj++) {
      int ka = k0 + 2 * jj, kb = ka + 1;
      float x0 = (n < S_DIM && ka < E_DIM) ? 128.f * Bm[n * E_DIM + ka] : 0.f;
      float x1 = (n < S_DIM && kb < E_DIM) ? 128.f * Bm[n * E_DIM + kb] : 0.f;
      HU1 h0, h1; h0.h = (_Float16)x0; h1.h = (_Float16)x1;
      wv[jj] = (uint32_t)h0.u | ((uint32_t)h1.u << 16);
    }
    uint4 o; o.x = wv[0]; o.y = wv[1]; o.z = wv[2]; o.w = wv[3];
    ((uint4*)Bfr)[idx] = o;
  } else {
    if (tid < NBATCH) out[tid] = 0.f;
  }
}

// ---- fused recursion, R9 + conflict surgery ----
// QL block-swizzle: element Q[m][k] stored at row m, 8-f16 block
//   bk' = (k>>3) ^ ((m>>2)&3) ^ (((k>>3)&1)<<2)
// -> write u16s land 2 lanes/bank; read b128s land ~2 lanes/bank (free).
// All LDS offsets loop-invariant (precomputed). MFMA chains split 5+5 / 2+2.
__global__ __launch_bounds__(640, 3)
void hmm_fused(const uint32_t* __restrict__ Apk,
               const uint32_t* __restrict__ Bfr,
               const float* __restrict__ inp,
               const float* __restrict__ Ivec,
               float* __restrict__ out) {
  __shared__ __attribute__((aligned(16))) _Float16 inH[2][16 * FH];
  __shared__ __attribute__((aligned(16))) _Float16 QL[2][16 * QSTR];
  __shared__ float zslot[16];
  int c = blockIdx.x, bbase = blockIdx.y * 16;
  int tid = threadIdx.x, lane = tid & 63, w = tid >> 6;
  int gl = lane & 15, quad = lane >> 4;

  half8 bfA[2][10], bfB[2][4];
#pragma unroll
  for (int q = 0; q < 2; q++) {
#pragma unroll
    for (int kt = 0; kt < 10; kt++)
      bfA[q][kt] = h8_from_u4(((const uint4*)Apk)[((w * 2 + q) * 10 + kt) * 64 + lane]);
#pragma unroll
    for (int kt = 0; kt < 4; kt++)
      bfB[q][kt] = h8_from_u4(((const uint4*)Bfr)[((w * 2 + q) * 4 + kt) * 64 + lane]);
  }
#pragma unroll
  for (int q = 0; q < 2; q++) {
#pragma unroll
    for (int kt = 0; kt < 10; kt++) asm volatile("" : "+v"(bfA[q][kt]));
#pragma unroll
    for (int kt = 0; kt < 4; kt++)  asm volatile("" : "+v"(bfB[q][kt]));
  }

  // precomputed swizzled LDS offsets (f16 units), all loop-invariant
  int wOff[2][4];   // write: (q, r) -> row (quad*4+r), col block of k=(w*2+q)*16+gl
#pragma unroll
  for (int q = 0; q < 2; q++) {
    int k = (w * 2 + q) * 16 + gl;
    int bk = k >> 3, sub = k & 7;
#pragma unroll
    for (int r = 0; r < 4; r++) {
      int m = quad * 4 + r;
      int bkw = bk ^ ((m >> 2) & 3) ^ ((bk & 1) << 2);
      wOff[q][r] = m * QSTR + bkw * 8 + sub;
    }
  }
  int rOff[10];     // read: kt -> row gl, logical block kt*4+quad
#pragma unroll
  for (int kt = 0; kt < 10; kt++) {
    int bk = kt * 4 + quad;
    int bkr = bk ^ ((gl >> 2) & 3) ^ ((bk & 1) << 2);
    rOff[kt] = gl * QSTR + bkr * 8;
  }

  // P init in C-layout
  float Pa[2][4];
#pragma unroll
  for (int q = 0; q < 2; q++) {
    int n = (w * 2 + q) * 16 + gl;
    float v = (n < S_DIM) ? (c == 0 ? Ivec[n] : 1.0f) : 0.f;
#pragma unroll
    for (int r = 0; r < 4; r++) Pa[q][r] = v;
  }
  if (tid < 16) zslot[tid] = 0.f;

  int t_first = (c == 0) ? 1 : (c * CHL - WARM + 1);
  int nstep   = (c == 0) ? (CHL - 1) : (CHL + WARM - 1);   // 31 or 35
  int iw      = (c == 0) ? -1 : (WARM - 1);                // z at t = c*CHL-1
  int t_last  = t_first - 1 + nstep;

  // stage inH[0] <- rows at t0 = t_first-1; prefetch t_first into registers
  {
    int t0 = t_first - 1;
#pragma unroll
    for (int s = 0; s < 2; s++) {
      int flat = tid + s * 640;
      if (flat < 1024) {
        int r = flat >> 6, c2 = flat & 63;
        float2 v; v.x = 0.f; v.y = 0.f;
        if (c2 < 63) v = *(const float2*)(inp + ((size_t)(bbase + r) * T_LEN + t0) * E_DIM + 2 * c2);
        HU1 a, b; a.h = (_Float16)v.x; b.h = (_Float16)v.y;
        *(uint32_t*)&inH[0][r * FH + 2 * c2] = (uint32_t)a.u | ((uint32_t)b.u << 16);
      }
    }
  }
  float2 g[2];
#pragma unroll
  for (int s = 0; s < 2; s++) {
    int flat = tid + s * 640;
    g[s].x = 0.f; g[s].y = 0.f;
    if (flat < 1024) {
      int r = flat >> 6, c2 = flat & 63;
      if (c2 < 63) g[s] = *(const float2*)(inp + ((size_t)(bbase + r) * T_LEN + t_first) * E_DIM + 2 * c2);
    }
  }
  float llw = 0.f;
  __syncthreads();

  for (int i = 0; i <= nstep; i++) {
    int cur = i & 1, nxt = cur ^ 1;
    // ---- phase a: E-MFMA from inH[cur], split 2+2 chains
    floatx4 Ea0a = (floatx4){0.f, 0.f, 0.f, 0.f}, Ea0b = Ea0a;
    floatx4 Ea1a = Ea0a, Ea1b = Ea0a;
    {
      half8 af0 = h8_from_u4(*(const uint4*)&inH[cur][gl * FH + 0 * 32 + quad * 8]);
      half8 af1 = h8_from_u4(*(const uint4*)&inH[cur][gl * FH + 1 * 32 + quad * 8]);
      half8 af2 = h8_from_u4(*(const uint4*)&inH[cur][gl * FH + 2 * 32 + quad * 8]);
      half8 af3 = h8_from_u4(*(const uint4*)&inH[cur][gl * FH + 3 * 32 + quad * 8]);
      Ea0a = __builtin_amdgcn_mfma_f32_16x16x32_f16(af0, bfB[0][0], Ea0a, 0, 0, 0);
      Ea1a = __builtin_amdgcn_mfma_f32_16x16x32_f16(af0, bfB[1][0], Ea1a, 0, 0, 0);
      Ea0b = __builtin_amdgcn_mfma_f32_16x16x32_f16(af1, bfB[0][1], Ea0b, 0, 0, 0);
      Ea1b = __builtin_amdgcn_mfma_f32_16x16x32_f16(af1, bfB[1][1], Ea1b, 0, 0, 0);
      Ea0a = __builtin_amdgcn_mfma_f32_16x16x32_f16(af2, bfB[0][2], Ea0a, 0, 0, 0);
      Ea1a = __builtin_amdgcn_mfma_f32_16x16x32_f16(af2, bfB[1][2], Ea1a, 0, 0, 0);
      Ea0b = __builtin_amdgcn_mfma_f32_16x16x32_f16(af3, bfB[0][3], Ea0b, 0, 0, 0);
      Ea1b = __builtin_amdgcn_mfma_f32_16x16x32_f16(af3, bfB[1][3], Ea1b, 0, 0, 0);
    }
    // Q = P (.) E  (registers; identical C-layout)
    float qv[2][4];
#pragma unroll
    for (int r = 0; r < 4; r++) {
      qv[0][r] = Pa[0][r] * (Ea0a[r] + Ea0b[r]);
      qv[1][r] = Pa[1][r] * (Ea1a[r] + Ea1b[r]);
    }
    // checkpoints: z[m] = sum_n Q[m][n]
    if (i == iw || i == nstep) {
      float s0 = qv[0][0] + qv[1][0], s1 = qv[0][1] + qv[1][1];
      float s2 = qv[0][2] + qv[1][2], s3 = qv[0][3] + qv[1][3];
#pragma unroll
      for (int off = 1; off <= 8; off <<= 1) {
        s0 += __shfl_xor(s0, off); s1 += __shfl_xor(s1, off);
        s2 += __shfl_xor(s2, off); s3 += __shfl_xor(s3, off);
      }
      if (gl == 0) {
        atomicAdd(&zslot[quad * 4 + 0], s0);
        atomicAdd(&zslot[quad * 4 + 1], s1);
        atomicAdd(&zslot[quad * 4 + 2], s2);
        atomicAdd(&zslot[quad * 4 + 3], s3);
      }
    }
    // write Q -> swizzled granule layout
#pragma unroll
    for (int q = 0; q < 2; q++)
#pragma unroll
      for (int r = 0; r < 4; r++)
        QL[cur][wOff[q][r]] = (_Float16)qv[q][r];
    // commit prefetched rows (t_first+i) -> inH[nxt]
    if (i < nstep) {
#pragma unroll
      for (int s = 0; s < 2; s++) {
        int flat = tid + s * 640;
        if (flat < 1024) {
          int r = flat >> 6, c2 = flat & 63;
          HU1 a, b; a.h = (_Float16)g[s].x; b.h = (_Float16)g[s].y;
          uint32_t pv = (c2 < 63) ? ((uint32_t)a.u | ((uint32_t)b.u << 16)) : 0u;
          *(uint32_t*)&inH[nxt][r * FH + 2 * c2] = pv;
        }
      }
    }
    __syncthreads();   // the ONLY barrier per step
    if (i == iw && tid < 16) { llw = logf(zslot[tid]); zslot[tid] = 0.f; }
    if (i == nstep) {
      if (tid < 16) {
        float lle = logf(zslot[tid]);
        atomicAdd(&out[bbase + tid], lle - llw - 32.0f * 4.852030263919617f);
      }
      break;
    }
    // ---- phase b: issue loads for t+1; P = Q @ A with 5+5 split chains
    {
      int tp = t_first + i + 1; if (tp > t_last) tp = t_last;
#pragma unroll
      for (int s = 0; s < 2; s++) {
        int flat = tid + s * 640;
        g[s].x = 0.f; g[s].y = 0.f;
        if (flat < 1024) {
          int r = flat >> 6, c2 = flat & 63;
          if (c2 < 63) g[s] = *(const float2*)(inp + ((size_t)(bbase + r) * T_LEN + tp) * E_DIM + 2 * c2);
        }
      }
    }
    floatx4 a0a = (floatx4){0.f, 0.f, 0.f, 0.f}, a0b = a0a, a1a = a0a, a1b = a0a;
#pragma unroll
    for (int kt = 0; kt < 10; kt += 2) {
      half8 afv0 = h8_from_u4(*(const uint4*)&QL[cur][rOff[kt]]);
      half8 afv1 = h8_from_u4(*(const uint4*)&QL[cur][rOff[kt + 1]]);
      a0a = __builtin_amdgcn_mfma_f32_16x16x32_f16(afv0, bfA[0][kt], a0a, 0, 0, 0);
      a1a = __builtin_amdgcn_mfma_f32_16x16x32_f16(afv0, bfA[1][kt], a1a, 0, 0, 0);
      a0b = __builtin_amdgcn_mfma_f32_16x16x32_f16(afv1, bfA[0][kt + 1], a0b, 0, 0, 0);
      a1b = __builtin_amdgcn_mfma_f32_16x16x32_f16(afv1, bfA[1][kt + 1], a1b, 0, 0, 0);
    }
#pragma unroll
    for (int r = 0; r < 4; r++) { Pa[0][r] = a0a[r] + a0b[r]; Pa[1][r] = a1a[r] + a1b[r]; }
  }
}

extern "C" void kernel_launch(void* const* d_in, const int* in_sizes, int n_in,
                              void* d_out, int out_size, void* d_ws, size_t ws_size,
                              hipStream_t stream) {
  const float* inp = (const float*)d_in[0];   // [32,4096,126]
  const float* A   = (const float*)d_in[1];   // [308,308]
  const float* Bm  = (const float*)d_in[2];   // [308,126]
  const float* Iv  = (const float*)d_in[3];   // [308]
  float* out = (float*)d_out;                 // [32]

  uint8_t* ws = (uint8_t*)d_ws;
  uint32_t* Apk = (uint32_t*)(ws);                 // 200 KiB
  uint32_t* Bfr = (uint32_t*)(ws + (256u << 10));  // 80 KiB

  hipLaunchKernelGGL(init_pack, dim3(71), dim3(256), 0, stream, A, Bm, Apk, Bfr, out);
  hipLaunchKernelGGL(hmm_fused, dim3(NCHUNK, NBATCH / 16), dim3(640), 0, stream,
                     Apk, Bfr, inp, Iv, out);
}

// Round 11
// 159.917 us; speedup vs baseline: 1.0741x; 1.0741x over previous
//
#include <hip/hip_runtime.h>
#include <cstdint>

#define T_LEN 4096
#define S_DIM 308
#define S_PAD 320
#define E_DIM 126
#define NBATCH 32
#define NCHUNK 256
#define CHL 16
#define WARM 4     // contraction ~0.03-0.07/step -> <=1e-3 abs per chunk boundary
#define FH 136     // inH row stride (f16)
#define QSTR 336   // QL row stride (f16), R9 linear layout (R10 swizzle REVERTED: it raised conflicts)

typedef _Float16 half8 __attribute__((ext_vector_type(8)));
typedef float floatx4 __attribute__((ext_vector_type(4)));

union HU8 { uint4 u; half8 h; };
union HU1 { uint16_t u; _Float16 h; };

__device__ __forceinline__ half8 h8_from_u4(uint4 v) { HU8 t; t.u = v; return t.h; }

// ---- merged init: blocks 0..49 pack A-frags, 50..69 pack B-frags, 70 zeroes out ----
__global__ __launch_bounds__(256) void init_pack(const float* __restrict__ A,
                                                 const float* __restrict__ Bm,
                                                 uint32_t* __restrict__ Apk,
                                                 uint32_t* __restrict__ Bfr,
                                                 float* __restrict__ out) {
  int blk = blockIdx.x, tid = threadIdx.x;
  if (blk < 50) {
    int idx = blk * 256 + tid;                 // 200 tiles * 64 lanes
    int lane = idx & 63, tile = idx >> 6;
    int kt = tile % 10, nt = tile / 10;
    int n  = nt * 16 + (lane & 15);
    int k0 = kt * 32 + (lane >> 4) * 8;
    uint32_t wv[4];
#pragma unroll
    for (int jj = 0; jj < 4; jj++) {
      int ka = k0 + 2 * jj, kb = ka + 1;
      float x0 = (n < S_DIM && ka < S_DIM) ? A[ka * S_DIM + n] : 0.f;
      float x1 = (n < S_DIM && kb < S_DIM) ? A[kb * S_DIM + n] : 0.f;
      HU1 h0, h1; h0.h = (_Float16)x0; h1.h = (_Float16)x1;
      wv[jj] = (uint32_t)h0.u | ((uint32_t)h1.u << 16);
    }
    uint4 o; o.x = wv[0]; o.y = wv[1]; o.z = wv[2]; o.w = wv[3];
    ((uint4*)Apk)[idx] = o;
  } else if (blk < 70) {
    int idx = (blk - 50) * 256 + tid;          // 80 tiles * 64 lanes
    int lane = idx & 63, tile = idx >> 6;
    int kt = tile % 4, nt = tile / 4;
    int n  = nt * 16 + (lane & 15);
    int k0 = kt * 32 + (lane >> 4) * 8;
    uint32_t wv[4];
#pragma unroll
    for (int jj = 0; jj < 4; jj++) {
      int ka = k0 + 2 * jj, kb = ka + 1;
      float x0 = (n < S_DIM && ka < E_DIM) ? 128.f * Bm[n * E_DIM + ka] : 0.f;
      float x1 = (n < S_DIM && kb < E_DIM) ? 128.f * Bm[n * E_DIM + kb] : 0.f;
      HU1 h0, h1; h0.h = (_Float16)x0; h1.h = (_Float16)x1;
      wv[jj] = (uint32_t)h0.u | ((uint32_t)h1.u << 16);
    }
    uint4 o; o.x = wv[0]; o.y = wv[1]; o.z = wv[2]; o.w = wv[3];
    ((uint4*)Bfr)[idx] = o;
  } else {
    if (tid < NBATCH) out[tid] = 0.f;
  }
}

// ---- fused recursion (R9 structure), CHL=16 -> 512 blocks, 2 blocks/CU ----
// Per step: a) E-MFMA (8, split 2+2) from f16-staged inp rows; Q = P (.) E in
// registers (shared C-layout); scatter Q -> QL[i&1] (R9 linear layout);
// commit prefetched inp rows; b) ONE barrier; P = Q @ A (20 MFMA, split 5+5);
// issue t+2 loads. Two independent blocks per CU overlap each other's
// barrier-drain latency (R9/R10 measured ~50% latency stall at 1 block/CU).
__global__ __launch_bounds__(640, 3)
void hmm_fused(const uint32_t* __restrict__ Apk,
               const uint32_t* __restrict__ Bfr,
               const float* __restrict__ inp,
               const float* __restrict__ Ivec,
               float* __restrict__ out) {
  __shared__ __attribute__((aligned(16))) _Float16 inH[2][16 * FH];
  __shared__ __attribute__((aligned(16))) _Float16 QL[2][16 * QSTR];
  __shared__ float zslot[16];
  int c = blockIdx.x, bbase = blockIdx.y * 16;
  int tid = threadIdx.x, lane = tid & 63, w = tid >> 6;
  int gl = lane & 15, quad = lane >> 4;

  half8 bfA[2][10], bfB[2][4];
#pragma unroll
  for (int q = 0; q < 2; q++) {
#pragma unroll
    for (int kt = 0; kt < 10; kt++)
      bfA[q][kt] = h8_from_u4(((const uint4*)Apk)[((w * 2 + q) * 10 + kt) * 64 + lane]);
#pragma unroll
    for (int kt = 0; kt < 4; kt++)
      bfB[q][kt] = h8_from_u4(((const uint4*)Bfr)[((w * 2 + q) * 4 + kt) * 64 + lane]);
  }
#pragma unroll
  for (int q = 0; q < 2; q++) {
#pragma unroll
    for (int kt = 0; kt < 10; kt++) asm volatile("" : "+v"(bfA[q][kt]));
#pragma unroll
    for (int kt = 0; kt < 4; kt++)  asm volatile("" : "+v"(bfB[q][kt]));
  }

  // P init in C-layout
  float Pa[2][4];
#pragma unroll
  for (int q = 0; q < 2; q++) {
    int n = (w * 2 + q) * 16 + gl;
    float v = (n < S_DIM) ? (c == 0 ? Ivec[n] : 1.0f) : 0.f;
#pragma unroll
    for (int r = 0; r < 4; r++) Pa[q][r] = v;
  }
  if (tid < 16) zslot[tid] = 0.f;

  int t_first = (c == 0) ? 1 : (c * CHL - WARM + 1);
  int nstep   = (c == 0) ? (CHL - 1) : (CHL + WARM - 1);   // 15 or 19
  int iw      = (c == 0) ? -1 : (WARM - 1);                // z at t = c*CHL-1
  int t_last  = t_first - 1 + nstep;

  // stage inH[0] <- rows at t0 = t_first-1; prefetch t_first into registers
  {
    int t0 = t_first - 1;
#pragma unroll
    for (int s = 0; s < 2; s++) {
      int flat = tid + s * 640;
      if (flat < 1024) {
        int r = flat >> 6, c2 = flat & 63;
        float2 v; v.x = 0.f; v.y = 0.f;
        if (c2 < 63) v = *(const float2*)(inp + ((size_t)(bbase + r) * T_LEN + t0) * E_DIM + 2 * c2);
        HU1 a, b; a.h = (_Float16)v.x; b.h = (_Float16)v.y;
        *(uint32_t*)&inH[0][r * FH + 2 * c2] = (uint32_t)a.u | ((uint32_t)b.u << 16);
      }
    }
  }
  float2 g[2];
#pragma unroll
  for (int s = 0; s < 2; s++) {
    int flat = tid + s * 640;
    g[s].x = 0.f; g[s].y = 0.f;
    if (flat < 1024) {
      int r = flat >> 6, c2 = flat & 63;
      if (c2 < 63) g[s] = *(const float2*)(inp + ((size_t)(bbase + r) * T_LEN + t_first) * E_DIM + 2 * c2);
    }
  }
  float llw = 0.f;
  __syncthreads();

  for (int i = 0; i <= nstep; i++) {
    int cur = i & 1, nxt = cur ^ 1;
    // ---- phase a: E-MFMA from inH[cur], split 2+2 chains
    floatx4 Ea0a = (floatx4){0.f, 0.f, 0.f, 0.f}, Ea0b = Ea0a;
    floatx4 Ea1a = Ea0a, Ea1b = Ea0a;
    {
      half8 af0 = h8_from_u4(*(const uint4*)&inH[cur][gl * FH + 0 * 32 + quad * 8]);
      half8 af1 = h8_from_u4(*(const uint4*)&inH[cur][gl * FH + 1 * 32 + quad * 8]);
      half8 af2 = h8_from_u4(*(const uint4*)&inH[cur][gl * FH + 2 * 32 + quad * 8]);
      half8 af3 = h8_from_u4(*(const uint4*)&inH[cur][gl * FH + 3 * 32 + quad * 8]);
      Ea0a = __builtin_amdgcn_mfma_f32_16x16x32_f16(af0, bfB[0][0], Ea0a, 0, 0, 0);
      Ea1a = __builtin_amdgcn_mfma_f32_16x16x32_f16(af0, bfB[1][0], Ea1a, 0, 0, 0);
      Ea0b = __builtin_amdgcn_mfma_f32_16x16x32_f16(af1, bfB[0][1], Ea0b, 0, 0, 0);
      Ea1b = __builtin_amdgcn_mfma_f32_16x16x32_f16(af1, bfB[1][1], Ea1b, 0, 0, 0);
      Ea0a = __builtin_amdgcn_mfma_f32_16x16x32_f16(af2, bfB[0][2], Ea0a, 0, 0, 0);
      Ea1a = __builtin_amdgcn_mfma_f32_16x16x32_f16(af2, bfB[1][2], Ea1a, 0, 0, 0);
      Ea0b = __builtin_amdgcn_mfma_f32_16x16x32_f16(af3, bfB[0][3], Ea0b, 0, 0, 0);
      Ea1b = __builtin_amdgcn_mfma_f32_16x16x32_f16(af3, bfB[1][3], Ea1b, 0, 0, 0);
    }
    // Q = P (.) E  (registers; identical C-layout)
    float qv[2][4];
#pragma unroll
    for (int r = 0; r < 4; r++) {
      qv[0][r] = Pa[0][r] * (Ea0a[r] + Ea0b[r]);
      qv[1][r] = Pa[1][r] * (Ea1a[r] + Ea1b[r]);
    }
    // checkpoints: z[m] = sum_n Q[m][n]
    if (i == iw || i == nstep) {
      float s0 = qv[0][0] + qv[1][0], s1 = qv[0][1] + qv[1][1];
      float s2 = qv[0][2] + qv[1][2], s3 = qv[0][3] + qv[1][3];
#pragma unroll
      for (int off = 1; off <= 8; off <<= 1) {
        s0 += __shfl_xor(s0, off); s1 += __shfl_xor(s1, off);
        s2 += __shfl_xor(s2, off); s3 += __shfl_xor(s3, off);
      }
      if (gl == 0) {
        atomicAdd(&zslot[quad * 4 + 0], s0);
        atomicAdd(&zslot[quad * 4 + 1], s1);
        atomicAdd(&zslot[quad * 4 + 2], s2);
        atomicAdd(&zslot[quad * 4 + 3], s3);
      }
    }
    // write Q -> granule [m][k] (A-operand layout for phase b), R9 linear addressing
#pragma unroll
    for (int q = 0; q < 2; q++) {
      int k = (w * 2 + q) * 16 + gl;
#pragma unroll
      for (int r = 0; r < 4; r++)
        QL[cur][(quad * 4 + r) * QSTR + k] = (_Float16)qv[q][r];
    }
    // commit prefetched rows (t_first+i) -> inH[nxt]
    if (i < nstep) {
#pragma unroll
      for (int s = 0; s < 2; s++) {
        int flat = tid + s * 640;
        if (flat < 1024) {
          int r = flat >> 6, c2 = flat & 63;
          HU1 a, b; a.h = (_Float16)g[s].x; b.h = (_Float16)g[s].y;
          uint32_t pv = (c2 < 63) ? ((uint32_t)a.u | ((uint32_t)b.u << 16)) : 0u;
          *(uint32_t*)&inH[nxt][r * FH + 2 * c2] = pv;
        }
      }
    }
    __syncthreads();   // the ONLY barrier per step
    if (i == iw && tid < 16) { llw = logf(zslot[tid]); zslot[tid] = 0.f; }
    if (i == nstep) {
      if (tid < 16) {
        float lle = logf(zslot[tid]);
        // CHL accounted steps between checkpoints, each carrying one x128
        atomicAdd(&out[bbase + tid], lle - llw - (float)CHL * 4.852030263919617f);
      }
      break;
    }
    // ---- phase b: issue loads for t+1; P = Q @ A with 5+5 split chains
    {
      int tp = t_first + i + 1; if (tp > t_last) tp = t_last;
#pragma unroll
      for (int s = 0; s < 2; s++) {
        int flat = tid + s * 640;
        g[s].x = 0.f; g[s].y = 0.f;
        if (flat < 1024) {
          int r = flat >> 6, c2 = flat & 63;
          if (c2 < 63) g[s] = *(const float2*)(inp + ((size_t)(bbase + r) * T_LEN + tp) * E_DIM + 2 * c2);
        }
      }
    }
    floatx4 a0a = (floatx4){0.f, 0.f, 0.f, 0.f}, a0b = a0a, a1a = a0a, a1b = a0a;
#pragma unroll
    for (int kt = 0; kt < 10; kt += 2) {
      half8 afv0 = h8_from_u4(*(const uint4*)&QL[cur][gl * QSTR + kt * 32 + quad * 8]);
      half8 afv1 = h8_from_u4(*(const uint4*)&QL[cur][gl * QSTR + (kt + 1) * 32 + quad * 8]);
      a0a = __builtin_amdgcn_mfma_f32_16x16x32_f16(afv0, bfA[0][kt], a0a, 0, 0, 0);
      a1a = __builtin_amdgcn_mfma_f32_16x16x32_f16(afv0, bfA[1][kt], a1a, 0, 0, 0);
      a0b = __builtin_amdgcn_mfma_f32_16x16x32_f16(afv1, bfA[0][kt + 1], a0b, 0, 0, 0);
      a1b = __builtin_amdgcn_mfma_f32_16x16x32_f16(afv1, bfA[1][kt + 1], a1b, 0, 0, 0);
    }
#pragma unroll
    for (int r = 0; r < 4; r++) { Pa[0][r] = a0a[r] + a0b[r]; Pa[1][r] = a1a[r] + a1b[r]; }
  }
}

extern "C" void kernel_launch(void* const* d_in, const int* in_sizes, int n_in,
                              void* d_out, int out_size, void* d_ws, size_t ws_size,
                              hipStream_t stream) {
  const float* inp = (const float*)d_in[0];   // [32,4096,126]
  const float* A   = (const float*)d_in[1];   // [308,308]
  const float* Bm  = (const float*)d_in[2];   // [308,126]
  const float* Iv  = (const float*)d_in[3];   // [308]
  float* out = (float*)d_out;                 // [32]

  uint8_t* ws = (uint8_t*)d_ws;
  uint32_t* Apk = (uint32_t*)(ws);                 // 200 KiB
  uint32_t* Bfr = (uint32_t*)(ws + (256u << 10));  // 80 KiB

  hipLaunchKernelGGL(init_pack, dim3(71), dim3(256), 0, stream, A, Bm, Apk, Bfr, out);
  hipLaunchKernelGGL(hmm_fused, dim3(NCHUNK, NBATCH / 16), dim3(640), 0, stream,
                     Apk, Bfr, inp, Iv, out);
}